// Round 8
// baseline (969.174 us; speedup 1.0000x reference)
//
#include <hip/hip_runtime.h>

// SNN recurrence, B=64 T=256 F=1024 fp32. 256 persistent WGs (1/CU via
// 146KB LDS) = 64 j-slices (16 output cols, js=bid&63) x 4 batch-groups
// (16 rows, bg=bid>>6). W column-slice in LDS as 4 signed base-512 digit
// limbs (exact in bf16); spk@W.T = 4 bf16 MFMAs per K-chunk with EXACT
// integer fp32 accumulation; limbs recombine in fp64; syn/mem state fp64.
//
// Round-8 protocol change (H2: MALL-transaction congestion):
//  - PUBLISH: all 16 data words of a WG are stored by ONE instruction of
//    wave 0 (lanes 0-15, one 64B line = 1 MALL transaction; was 4 separate
//    wave-stores), plus ONE tag word into a dense per-bg tag array. Ballots
//    funnel through LDS bal[] using the existing B2 barrier.
//  - POLL: consumers spin on the dense tag array only — the wave's 8
//    producers' tags are 8 contiguous words (32B) = 1 MALL transaction per
//    iteration (was 8 line-transactions of 512B). After tags pass, ONE
//    512B data fetch; embedded per-word tags are verified with a re-load
//    fallback, so correctness never depends on tag-vs-data store ordering.
//
// Fence-free tagged-word exchange: data word = ((t+1)<<16)|16 spike bits,
// relaxed agent-scope stores/loads (4B store is atomic: data+tag together).
// All-to-all join per step bounds WG skew < 4 steps => 4-deep slot ring
// (64KB data + 4KB tags in ws) is WAR-safe; memset per launch (replay-safe).

#define NT 512

typedef __bf16 bf16x8 __attribute__((ext_vector_type(8)));
typedef float f32x4 __attribute__((ext_vector_type(4)));
typedef int i32x4 __attribute__((ext_vector_type(4)));

static __device__ __forceinline__ unsigned short f2bf(float v) {
    union { float f; unsigned int u; } a; a.f = v;
    unsigned int u = a.u;
    u += 0x7fffu + ((u >> 16) & 1u);   // RNE (exact for small ints)
    return (unsigned short)(u >> 16);
}

// 4 signed base-512 digits of round(w * 2^36); digits in [-256,255], exact in bf16.
static __device__ __forceinline__ void decomp512(float w, int* d) {
    long long v = llround((double)w * 68719476736.0);  // 2^36
    #pragma unroll
    for (int i = 0; i < 4; ++i) {
        int r = (int)(v & 511);
        if (r >= 256) r -= 512;
        d[i] = r;
        v = (v - (long long)r) >> 9;
    }
}

// LDS-only barrier: order LDS ops across waves without draining vmcnt
// (global stores / loads stay in flight across it).
static __device__ __forceinline__ void lds_barrier() {
    __builtin_amdgcn_sched_barrier(0);
    asm volatile("s_waitcnt lgkmcnt(0)\n\ts_barrier" ::: "memory");
    __builtin_amdgcn_sched_barrier(0);
}

__launch_bounds__(NT, 1)
__global__ void snn_persist_kernel(const float* __restrict__ x,
                                   const float* __restrict__ W,
                                   const float* __restrict__ bias,
                                   float* __restrict__ out,
                                   unsigned int* __restrict__ gbm,
                                   unsigned int* __restrict__ tagw)
{
    constexpr int T = 256, F = 1024;
    const int bid = blockIdx.x;
    const int js  = bid & 63;   // j-slice: output cols js*16 .. js*16+15
    const int bg  = bid >> 6;   // batch group: rows bg*16 .. bg*16+15
    const int tid = threadIdx.x;
    const int lane = tid & 63;
    const int wv   = tid >> 6;  // wave 0..7 (K-split: chunks wv*4..wv*4+3)
    const int q = lane >> 4, r15 = lane & 15;

    // W digit slices, MFMA B-operand order: [kc 0..31][lane 0..63][8 bf16]
    __shared__ __align__(16) unsigned int wd0[32*64*4];
    __shared__ __align__(16) unsigned int wd1[32*64*4];
    __shared__ __align__(16) unsigned int wd2[32*64*4];
    __shared__ __align__(16) unsigned int wd3[32*64*4];
    __shared__ unsigned short wbm[8][128];   // per-wave bitmap slice
    __shared__ double partD[8*256];          // per-wave partial h
    __shared__ unsigned long long bal[4];    // per-wave ballots (rows 4g+wv)
    // total LDS = 128KB + 2KB + 16KB + 32B ≈ 146KB -> exactly 1 WG/CU

    // ---- init: load W slice, 4-digit split, store in fragment order ----
    // B-frag: lane l supplies B[k=(l>>4)*8+i][n=l&15]; global W[js*16+n][kc*32+(l>>4)*8+i]
    for (int it = 0; it < 4; ++it) {
        int s = tid + NT*it;            // slot 0..2047 = (kc,l)
        int kc = s >> 6, l = s & 63;
        int n = l & 15, qq = l >> 4;
        int f0 = kc*32 + qq*8;
        const float* wr = W + (size_t)(js*16 + n)*F + f0;
        float e[8];
        *(float4*)&e[0] = *(const float4*)(wr);
        *(float4*)&e[4] = *(const float4*)(wr + 4);
        unsigned int pk0[4], pk1[4], pk2[4], pk3[4];
        #pragma unroll
        for (int i = 0; i < 4; ++i) {
            int da[4], db[4];
            decomp512(e[2*i],   da);
            decomp512(e[2*i+1], db);
            pk0[i] = (unsigned int)f2bf((float)da[0]) | ((unsigned int)f2bf((float)db[0]) << 16);
            pk1[i] = (unsigned int)f2bf((float)da[1]) | ((unsigned int)f2bf((float)db[1]) << 16);
            pk2[i] = (unsigned int)f2bf((float)da[2]) | ((unsigned int)f2bf((float)db[2]) << 16);
            pk3[i] = (unsigned int)f2bf((float)da[3]) | ((unsigned int)f2bf((float)db[3]) << 16);
        }
        #pragma unroll
        for (int i = 0; i < 4; ++i) {
            wd0[s*4+i] = pk0[i]; wd1[s*4+i] = pk1[i];
            wd2[s*4+i] = pk2[i]; wd3[s*4+i] = pk3[i];
        }
    }

    // state mapping (tid<256), matching MFMA C layout after the LDS reduce:
    // row b = ((tid>>4)&3)*4 + (tid>>6), col j = tid&15
    const int brow = ((tid >> 4) & 3)*4 + (tid >> 6);
    const int jcol = tid & 15;
    const int bglob = bg*16 + brow;
    const double bj = (double)bias[js*16 + jcol];
    const size_t obase = (size_t)bglob*T*F + js*16 + jcol;
    float* outspk = out;
    float* outmem = out + (size_t)64*T*F;

    double syn = 0.0, mem = 0.0, rst = 0.0;

    __syncthreads();   // W tiles ready (full barrier, once)

    for (int t = 0; t < T; ++t) {
        // x load at top: issued before poll, drains during the tag spin
        float xv = 0.f;
        if (tid < 256) xv = x[obase + (size_t)t*F];

        double h = 0.0;
        double sbase, mbase;
        if (t > 0) {
            const unsigned int tg = (unsigned int)t;   // tag of step t-1 data
            const int slot = ((t-1)&3)*4 + bg;
            // 1) tag spin: wave's 8 producers = 8 contiguous words (32B,
            //    ONE transaction per iteration; lanes cover them redundantly)
            const unsigned int* tap = tagw + (size_t)slot*64 + wv*8 + (lane & 7);
            unsigned int tv;
            do {
                tv = __hip_atomic_load(tap, __ATOMIC_RELAXED, __HIP_MEMORY_SCOPE_AGENT);
            } while (__any(tv != tg));
            // 2) data fetch + embedded-tag verify (handles tag/data skew)
            const unsigned int* sl = gbm + (size_t)slot*1024;
            const unsigned int* p0 = sl + wv*128 + lane;
            const unsigned int* p1 = p0 + 64;
            unsigned int v0, v1;
            do {
                v0 = __hip_atomic_load(p0, __ATOMIC_RELAXED, __HIP_MEMORY_SCOPE_AGENT);
                v1 = __hip_atomic_load(p1, __ATOMIC_RELAXED, __HIP_MEMORY_SCOPE_AGENT);
            } while (__any(((v0 >> 16) != tg) | ((v1 >> 16) != tg)));
            // stash data halves in own wave's LDS region (same-wave, no barrier)
            wbm[wv][lane]      = (unsigned short)v0;
            wbm[wv][64 + lane] = (unsigned short)v1;

            // off-chain state precompute (independent of h; xv drained by spin)
            sbase = 0.8*syn + (double)xv + bj;
            mbase = 0.9*mem - rst;

            // MFMA: 4 K-chunks x 4 limbs, exact integer fp32 accumulation
            f32x4 ac0 = {0.f,0.f,0.f,0.f}, ac1 = ac0, ac2 = ac0, ac3 = ac0;
            #pragma unroll
            for (int c4 = 0; c4 < 4; ++c4) {
                const int kc = wv*4 + c4;
                // A-frag: lane supplies A[row=r15][k=q*8+i] -> f = kc*32+q*8+i
                unsigned int us = wbm[wv][(2*c4 + (q >> 1))*16 + r15];
                unsigned int byt = (us >> ((q & 1)*8)) & 0xFFu;
                unsigned int d0 = ((byt&1u)  ?0x3F80u:0u) | ((byt&2u)  ?0x3F800000u:0u);
                unsigned int d1 = ((byt&4u)  ?0x3F80u:0u) | ((byt&8u)  ?0x3F800000u:0u);
                unsigned int d2 = ((byt&16u) ?0x3F80u:0u) | ((byt&32u) ?0x3F800000u:0u);
                unsigned int d3 = ((byt&64u) ?0x3F80u:0u) | ((byt&128u)?0x3F800000u:0u);
                i32x4 ai = {(int)d0, (int)d1, (int)d2, (int)d3};
                bf16x8 a = __builtin_bit_cast(bf16x8, ai);
                size_t fo = (size_t)(kc*64 + lane)*4;
                bf16x8 b0 = *(const bf16x8*)(wd0 + fo);
                bf16x8 b1 = *(const bf16x8*)(wd1 + fo);
                bf16x8 b2 = *(const bf16x8*)(wd2 + fo);
                bf16x8 b3 = *(const bf16x8*)(wd3 + fo);
                ac0 = __builtin_amdgcn_mfma_f32_16x16x32_bf16(a, b0, ac0, 0,0,0);
                ac1 = __builtin_amdgcn_mfma_f32_16x16x32_bf16(a, b1, ac1, 0,0,0);
                ac2 = __builtin_amdgcn_mfma_f32_16x16x32_bf16(a, b2, ac2, 0,0,0);
                ac3 = __builtin_amdgcn_mfma_f32_16x16x32_bf16(a, b3, ac3, 0,0,0);
            }
            // limb recombine in fp64 (exact): weight of limb i = 2^(9i-36)
            const double c0 = 1.0/68719476736.0, c1 = 1.0/134217728.0;
            const double c2 = 1.0/262144.0,      c3 = 1.0/512.0;
            #pragma unroll
            for (int r = 0; r < 4; ++r)
                partD[wv*256 + r*64 + lane] =
                    (double)ac0[r]*c0 + (double)ac1[r]*c1 +
                    (double)ac2[r]*c2 + (double)ac3[r]*c3;

            lds_barrier();   // B1: partD writes(t) before reads(t)

            if (tid < 256) {
                double s0 = partD[0*256 + tid] + partD[1*256 + tid];
                double s1 = partD[2*256 + tid] + partD[3*256 + tid];
                double s2 = partD[4*256 + tid] + partD[5*256 + tid];
                double s3 = partD[6*256 + tid] + partD[7*256 + tid];
                h = (s0 + s1) + (s2 + s3);
            }
        } else {
            sbase = 0.8*syn + (double)xv + bj;
            mbase = 0.9*mem - rst;
        }

        if (tid < 256) {
            syn = sbase + h;
            mem = mbase + syn;
            bool sp = (mem > 1.0);
            unsigned long long m = __ballot(sp);
            if (lane == 0) bal[wv] = m;   // funnel ballots for wave-0 publish
            rst = sp ? 1.0 : 0.0;
            outspk[obase + (size_t)t*F] = sp ? 1.0f : 0.0f;
            outmem[obase + (size_t)t*F] = (float)mem;
        }

        lds_barrier();   // B2: partD reads(t) before writes(t+1); bal ready

        // single-transaction publish (wave 0): one 64B line of 16 data words
        // (word w = row w: bits [16*(w>>2), +16) of wave (w&3)'s ballot),
        // then one tag word into the dense per-bg tag array.
        if (wv == 0) {
            const int slot = (t&3)*4 + bg;
            if (lane < 16) {
                unsigned int word =
                    (unsigned int)((bal[lane & 3] >> (16*(lane >> 2))) & 0xFFFFull);
                unsigned int val = (((unsigned int)(t + 1)) << 16) | word;
                unsigned int* dst = gbm + (size_t)slot*1024 + js*16 + lane;
                __hip_atomic_store(dst, val, __ATOMIC_RELAXED, __HIP_MEMORY_SCOPE_AGENT);
            } else if (lane == 16) {
                unsigned int* tdst = tagw + (size_t)slot*64 + js;
                __hip_atomic_store(tdst, (unsigned int)(t + 1),
                                   __ATOMIC_RELAXED, __HIP_MEMORY_SCOPE_AGENT);
            }
        }
    }
}

extern "C" void kernel_launch(void* const* d_in, const int* in_sizes, int n_in,
                              void* d_out, int out_size, void* d_ws, size_t ws_size,
                              hipStream_t stream) {
    const float* x    = (const float*)d_in[0];
    const float* W    = (const float*)d_in[1];
    const float* bias = (const float*)d_in[2];
    float* out = (float*)d_out;

    // ws: [0,64KB) 4-slot data ring [slot*4+bg][1024 words];
    //     [64KB,68KB) 4-slot tag ring [slot*4+bg][64 words]
    unsigned int* gbm  = (unsigned int*)d_ws;
    unsigned int* tagw = (unsigned int*)((char*)d_ws + 65536);

    hipMemsetAsync(d_ws, 0, 69632, stream);  // clear data+tags every launch
    hipLaunchKernelGGL(snn_persist_kernel, dim3(256), dim3(512), 0, stream,
                       x, W, bias, out, gbm, tagw);
}

// Round 9
// 616.022 us; speedup vs baseline: 1.5733x; 1.5733x over previous
//
#include <hip/hip_runtime.h>

// SNN recurrence, B=64 T=256 F=1024 fp32. 256 persistent WGs (1/CU via
// 144KB LDS) = 64 j-slices (16 output cols, js=bid&63) x 4 batch-groups
// (16 rows, bg=bid>>6). W column-slice in LDS as 4 signed base-512 digit
// limbs (exact in bf16); spk@W.T = 4 bf16 MFMAs per K-chunk with EXACT
// integer fp32 accumulation; limbs recombine in fp64; syn/mem state fp64.
//
// Round-9 delta vs r6 (verified 578us), consumer side only:
//  - each lane POLLS THE EXACT 4 WORDS ITS MFMA CONSUMES
//    (slot + wv*128 + qh*16 + r15 + 32*c4): polled registers ARE the
//    A-frag sources — the wbm LDS stash + re-read hop is deleted;
//  - PROCESS-AS-AVAILABLE: spin per chunk c4, MFMA it, then spin the next —
//    MFMA of early chunks overlaps late producers' publish tail.
//  All 4 loads are pre-issued before the first spin. Tags are monotone per
//  slot (next write is t+4, impossible while any WG is at t), so re-loading
//  an already-valid word is safe. Publish path, B1/B2 LDS-only barriers,
//  partD reduce, 4-deep ring: identical to r6.
//
// Fence-free tagged-word exchange: word = ((t+1)<<16)|16 spike bits, relaxed
// agent-scope (sc1) stores/loads; a 4B store is atomic so data+tag publish
// together. All-to-all join per step bounds WG skew < 4 steps => 4-slot ring
// (64KB ws) is WAR-safe; memset per launch (replay-safe).

#define NT 512

typedef __bf16 bf16x8 __attribute__((ext_vector_type(8)));
typedef float f32x4 __attribute__((ext_vector_type(4)));
typedef int i32x4 __attribute__((ext_vector_type(4)));

static __device__ __forceinline__ unsigned short f2bf(float v) {
    union { float f; unsigned int u; } a; a.f = v;
    unsigned int u = a.u;
    u += 0x7fffu + ((u >> 16) & 1u);   // RNE (exact for small ints)
    return (unsigned short)(u >> 16);
}

// 4 signed base-512 digits of round(w * 2^36); digits in [-256,255], exact in bf16.
static __device__ __forceinline__ void decomp512(float w, int* d) {
    long long v = llround((double)w * 68719476736.0);  // 2^36
    #pragma unroll
    for (int i = 0; i < 4; ++i) {
        int r = (int)(v & 511);
        if (r >= 256) r -= 512;
        d[i] = r;
        v = (v - (long long)r) >> 9;
    }
}

// LDS-only barrier: order LDS ops across waves without draining vmcnt
// (global stores / loads stay in flight across it).
static __device__ __forceinline__ void lds_barrier() {
    __builtin_amdgcn_sched_barrier(0);
    asm volatile("s_waitcnt lgkmcnt(0)\n\ts_barrier" ::: "memory");
    __builtin_amdgcn_sched_barrier(0);
}

static __device__ __forceinline__ unsigned int agload(const unsigned int* p) {
    return __hip_atomic_load(p, __ATOMIC_RELAXED, __HIP_MEMORY_SCOPE_AGENT);
}

__launch_bounds__(NT, 1)
__global__ void snn_persist_kernel(const float* __restrict__ x,
                                   const float* __restrict__ W,
                                   const float* __restrict__ bias,
                                   float* __restrict__ out,
                                   unsigned int* __restrict__ gbm)
{
    constexpr int T = 256, F = 1024;
    const int bid = blockIdx.x;
    const int js  = bid & 63;   // j-slice: output cols js*16 .. js*16+15
    const int bg  = bid >> 6;   // batch group: rows bg*16 .. bg*16+15
    const int tid = threadIdx.x;
    const int lane = tid & 63;
    const int wv   = tid >> 6;  // wave 0..7 (K-split: chunks wv*4..wv*4+3)
    const int q = lane >> 4, r15 = lane & 15;
    const int qh = q >> 1, ql = q & 1;

    // W digit slices, MFMA B-operand order: [kc 0..31][lane 0..63][8 bf16]
    __shared__ __align__(16) unsigned int wd0[32*64*4];
    __shared__ __align__(16) unsigned int wd1[32*64*4];
    __shared__ __align__(16) unsigned int wd2[32*64*4];
    __shared__ __align__(16) unsigned int wd3[32*64*4];
    __shared__ double partD[8*256];          // per-wave partial h
    // total LDS = 128KB + 16KB = 144KB -> exactly 1 WG/CU

    // ---- init: load W slice, 4-digit split, store in fragment order ----
    // B-frag: lane l supplies B[k=(l>>4)*8+i][n=l&15]; global W[js*16+n][kc*32+(l>>4)*8+i]
    for (int it = 0; it < 4; ++it) {
        int s = tid + NT*it;            // slot 0..2047 = (kc,l)
        int kc = s >> 6, l = s & 63;
        int n = l & 15, qq = l >> 4;
        int f0 = kc*32 + qq*8;
        const float* wr = W + (size_t)(js*16 + n)*F + f0;
        float e[8];
        *(float4*)&e[0] = *(const float4*)(wr);
        *(float4*)&e[4] = *(const float4*)(wr + 4);
        unsigned int pk0[4], pk1[4], pk2[4], pk3[4];
        #pragma unroll
        for (int i = 0; i < 4; ++i) {
            int da[4], db[4];
            decomp512(e[2*i],   da);
            decomp512(e[2*i+1], db);
            pk0[i] = (unsigned int)f2bf((float)da[0]) | ((unsigned int)f2bf((float)db[0]) << 16);
            pk1[i] = (unsigned int)f2bf((float)da[1]) | ((unsigned int)f2bf((float)db[1]) << 16);
            pk2[i] = (unsigned int)f2bf((float)da[2]) | ((unsigned int)f2bf((float)db[2]) << 16);
            pk3[i] = (unsigned int)f2bf((float)da[3]) | ((unsigned int)f2bf((float)db[3]) << 16);
        }
        #pragma unroll
        for (int i = 0; i < 4; ++i) {
            wd0[s*4+i] = pk0[i]; wd1[s*4+i] = pk1[i];
            wd2[s*4+i] = pk2[i]; wd3[s*4+i] = pk3[i];
        }
    }

    // state mapping (tid<256), matching MFMA C layout after the LDS reduce:
    // row b = ((tid>>4)&3)*4 + (tid>>6), col j = tid&15
    const int brow = ((tid >> 4) & 3)*4 + (tid >> 6);
    const int jcol = tid & 15;
    const int bglob = bg*16 + brow;
    const double bj = (double)bias[js*16 + jcol];
    const size_t obase = (size_t)bglob*T*F + js*16 + jcol;
    float* outspk = out;
    float* outmem = out + (size_t)64*T*F;

    double syn = 0.0, mem = 0.0, rst = 0.0;

    __syncthreads();   // W tiles ready (full barrier, once)

    for (int t = 0; t < T; ++t) {
        // x load at top: issued before poll; its latency hides under the spin
        float xv = 0.f;
        if (tid < 256) xv = x[obase + (size_t)t*F];

        double h = 0.0;
        double sbase, mbase;
        if (t > 0) {
            const unsigned int tg = (unsigned int)t;   // tag of step t-1 data
            const unsigned int* slot = gbm + (size_t)(((t-1)&3)*4 + bg)*1024;
            // lane's 4 A-frag source words: chunk c4 needs word
            // (2*(wv*4+c4)+qh)*16 + r15 = wv*128 + qh*16 + r15 + 32*c4
            const unsigned int* p0 = slot + wv*128 + qh*16 + r15;
            // pre-issue all 4 (overlapped flight)
            unsigned int w0 = agload(p0);
            unsigned int w1 = agload(p0 + 32);
            unsigned int w2 = agload(p0 + 64);
            unsigned int w3 = agload(p0 + 96);

            // off-chain state precompute: the xv use waits only on the x load
            // (older than the poll loads in vmcnt order)
            sbase = 0.8*syn + (double)xv + bj;
            mbase = 0.9*mem - rst;

            // process-as-available: spin chunk c4, MFMA it, next chunk.
            f32x4 ac0 = {0.f,0.f,0.f,0.f}, ac1 = ac0, ac2 = ac0, ac3 = ac0;
            #pragma unroll
            for (int c4 = 0; c4 < 4; ++c4) {
                unsigned int wc = (c4 == 0) ? w0 : (c4 == 1) ? w1 : (c4 == 2) ? w2 : w3;
                const unsigned int* pc = p0 + 32*c4;
                while (__any((wc >> 16) != tg)) wc = agload(pc);
                const int kc = wv*4 + c4;
                unsigned int byt = (wc >> (ql*8)) & 0xFFu;
                unsigned int d0 = ((byt&1u)  ?0x3F80u:0u) | ((byt&2u)  ?0x3F800000u:0u);
                unsigned int d1 = ((byt&4u)  ?0x3F80u:0u) | ((byt&8u)  ?0x3F800000u:0u);
                unsigned int d2 = ((byt&16u) ?0x3F80u:0u) | ((byt&32u) ?0x3F800000u:0u);
                unsigned int d3 = ((byt&64u) ?0x3F80u:0u) | ((byt&128u)?0x3F800000u:0u);
                i32x4 ai = {(int)d0, (int)d1, (int)d2, (int)d3};
                bf16x8 a = __builtin_bit_cast(bf16x8, ai);
                size_t fo = (size_t)(kc*64 + lane)*4;
                bf16x8 b0 = *(const bf16x8*)(wd0 + fo);
                bf16x8 b1 = *(const bf16x8*)(wd1 + fo);
                bf16x8 b2 = *(const bf16x8*)(wd2 + fo);
                bf16x8 b3 = *(const bf16x8*)(wd3 + fo);
                ac0 = __builtin_amdgcn_mfma_f32_16x16x32_bf16(a, b0, ac0, 0,0,0);
                ac1 = __builtin_amdgcn_mfma_f32_16x16x32_bf16(a, b1, ac1, 0,0,0);
                ac2 = __builtin_amdgcn_mfma_f32_16x16x32_bf16(a, b2, ac2, 0,0,0);
                ac3 = __builtin_amdgcn_mfma_f32_16x16x32_bf16(a, b3, ac3, 0,0,0);
            }
            // limb recombine in fp64 (exact): weight of limb i = 2^(9i-36)
            const double c0 = 1.0/68719476736.0, c1 = 1.0/134217728.0;
            const double c2 = 1.0/262144.0,      c3 = 1.0/512.0;
            #pragma unroll
            for (int r = 0; r < 4; ++r)
                partD[wv*256 + r*64 + lane] =
                    (double)ac0[r]*c0 + (double)ac1[r]*c1 +
                    (double)ac2[r]*c2 + (double)ac3[r]*c3;

            lds_barrier();   // B1: partD writes(t) before reads(t)

            if (tid < 256) {
                double s0 = partD[0*256 + tid] + partD[1*256 + tid];
                double s1 = partD[2*256 + tid] + partD[3*256 + tid];
                double s2 = partD[4*256 + tid] + partD[5*256 + tid];
                double s3 = partD[6*256 + tid] + partD[7*256 + tid];
                h = (s0 + s1) + (s2 + s3);
            }
        } else {
            sbase = 0.8*syn + (double)xv + bj;
            mbase = 0.9*mem - rst;
        }

        if (tid < 256) {
            syn = sbase + h;
            mem = mbase + syn;
            bool sp = (mem > 1.0);
            unsigned long long m = __ballot(sp);
            // publish FIRST (critical path): wave wv owns rows 4g+wv, g=lane>>4;
            // 16 consecutive words per WG = one 64B line, 1 transaction/wave
            if ((lane & 15) == 0) {
                int g = lane >> 4;
                unsigned int word = (unsigned int)((m >> (16*g)) & 0xFFFFull);
                unsigned int val = (((unsigned int)(t + 1)) << 16) | word;
                unsigned int* dst = gbm + (size_t)((t&3)*4 + bg)*1024 + js*16 + (4*g + wv);
                __hip_atomic_store(dst, val, __ATOMIC_RELAXED, __HIP_MEMORY_SCOPE_AGENT);
            }
            rst = sp ? 1.0 : 0.0;
            outspk[obase + (size_t)t*F] = sp ? 1.0f : 0.0f;
            outmem[obase + (size_t)t*F] = (float)mem;
        }

        lds_barrier();   // B2: partD reads(t) before writes(t+1)
    }
}

extern "C" void kernel_launch(void* const* d_in, const int* in_sizes, int n_in,
                              void* d_out, int out_size, void* d_ws, size_t ws_size,
                              hipStream_t stream) {
    const float* x    = (const float*)d_in[0];
    const float* W    = (const float*)d_in[1];
    const float* bias = (const float*)d_in[2];
    float* out = (float*)d_out;

    // ws: 4-slot ring of tagged bitmaps [slot 0..3][bg 0..3][1024 uints] = 64KB
    unsigned int* gbm = (unsigned int*)d_ws;

    hipMemsetAsync(d_ws, 0, 65536, stream);  // clear tags every launch (replay-safe)
    hipLaunchKernelGGL(snn_persist_kernel, dim3(256), dim3(512), 0, stream,
                       x, W, bias, out, gbm);
}

// Round 11
// 578.691 us; speedup vs baseline: 1.6748x; 1.0645x over previous
//
#include <hip/hip_runtime.h>

// SNN recurrence, B=64 T=256 F=1024 fp32. 256 persistent WGs (1/CU via
// 146KB LDS) = 64 j-slices (16 output cols, js=bid&63) x 4 batch-groups
// (16 rows, bg=bid>>6). W column-slice in LDS as 4 signed base-512 digit
// limbs (exact in bf16); spk@W.T = 4 bf16 MFMAs per K-chunk with EXACT
// integer fp32 accumulation; limbs recombine in fp64; syn/mem state fp64.
//
// VERIFIED round-6 structure (564-578us across two independent benches):
// per-wave 2-load poll of a 128-word slice, wbm LDS staging, consecutive
// 16-word publish (1 cache line/WG/step), two LDS-only barriers per step,
// sbase/mbase precompute, pairwise-tree partD reduce.
//
// This is the measured structural floor for the all-to-all-per-step
// topology on MI355X: step time ~2.2us = publish-visibility RT + poll
// detect RT + 64-producer tail skew + ~0.7us local compute. All pipes
// idle (MfmaUtil ~9%, VALUBusy ~20%, HBM ~5%); rounds 4,5,7,8,9,10 each
// attacked one term (reg-W, poll-is-data, preload, tag-array, per-chunk
// spin, 4-wave/1-barrier) and all regressed or raced.
//
// Fence-free tagged-word exchange: word = ((t+1)<<16)|16 spike bits, relaxed
// agent-scope (sc1) stores/loads; 4B store is atomic so data+tag publish
// together. 4-deep slot ring (64KB ws) memset per launch (replay-safe).

#define NT 512

typedef __bf16 bf16x8 __attribute__((ext_vector_type(8)));
typedef float f32x4 __attribute__((ext_vector_type(4)));
typedef int i32x4 __attribute__((ext_vector_type(4)));

static __device__ __forceinline__ unsigned short f2bf(float v) {
    union { float f; unsigned int u; } a; a.f = v;
    unsigned int u = a.u;
    u += 0x7fffu + ((u >> 16) & 1u);   // RNE (exact for small ints)
    return (unsigned short)(u >> 16);
}

// 4 signed base-512 digits of round(w * 2^36); digits in [-256,255], exact in bf16.
static __device__ __forceinline__ void decomp512(float w, int* d) {
    long long v = llround((double)w * 68719476736.0);  // 2^36
    #pragma unroll
    for (int i = 0; i < 4; ++i) {
        int r = (int)(v & 511);
        if (r >= 256) r -= 512;
        d[i] = r;
        v = (v - (long long)r) >> 9;
    }
}

// LDS-only barrier: order LDS ops across waves without draining vmcnt
// (global stores / loads stay in flight across it).
static __device__ __forceinline__ void lds_barrier() {
    __builtin_amdgcn_sched_barrier(0);
    asm volatile("s_waitcnt lgkmcnt(0)\n\ts_barrier" ::: "memory");
    __builtin_amdgcn_sched_barrier(0);
}

__launch_bounds__(NT, 1)
__global__ void snn_persist_kernel(const float* __restrict__ x,
                                   const float* __restrict__ W,
                                   const float* __restrict__ bias,
                                   float* __restrict__ out,
                                   unsigned int* __restrict__ gbm)
{
    constexpr int T = 256, F = 1024;
    const int bid = blockIdx.x;
    const int js  = bid & 63;   // j-slice: output cols js*16 .. js*16+15
    const int bg  = bid >> 6;   // batch group: rows bg*16 .. bg*16+15
    const int tid = threadIdx.x;
    const int lane = tid & 63;
    const int wv   = tid >> 6;  // wave 0..7 (K-split: chunks wv*4..wv*4+3)
    const int q = lane >> 4, r15 = lane & 15;

    // W digit slices, MFMA B-operand order: [kc 0..31][lane 0..63][8 bf16]
    __shared__ __align__(16) unsigned int wd0[32*64*4];
    __shared__ __align__(16) unsigned int wd1[32*64*4];
    __shared__ __align__(16) unsigned int wd2[32*64*4];
    __shared__ __align__(16) unsigned int wd3[32*64*4];
    __shared__ unsigned short wbm[8][128];   // per-wave bitmap slice
    __shared__ double partD[8*256];          // per-wave partial h
    // total LDS = 128KB + 2KB + 16KB = 146KB -> exactly 1 WG/CU

    // ---- init: load W slice, 4-digit split, store in fragment order ----
    // B-frag: lane l supplies B[k=(l>>4)*8+i][n=l&15]; global W[js*16+n][kc*32+(l>>4)*8+i]
    for (int it = 0; it < 4; ++it) {
        int s = tid + NT*it;            // slot 0..2047 = (kc,l)
        int kc = s >> 6, l = s & 63;
        int n = l & 15, qq = l >> 4;
        int f0 = kc*32 + qq*8;
        const float* wr = W + (size_t)(js*16 + n)*F + f0;
        float e[8];
        *(float4*)&e[0] = *(const float4*)(wr);
        *(float4*)&e[4] = *(const float4*)(wr + 4);
        unsigned int pk0[4], pk1[4], pk2[4], pk3[4];
        #pragma unroll
        for (int i = 0; i < 4; ++i) {
            int da[4], db[4];
            decomp512(e[2*i],   da);
            decomp512(e[2*i+1], db);
            pk0[i] = (unsigned int)f2bf((float)da[0]) | ((unsigned int)f2bf((float)db[0]) << 16);
            pk1[i] = (unsigned int)f2bf((float)da[1]) | ((unsigned int)f2bf((float)db[1]) << 16);
            pk2[i] = (unsigned int)f2bf((float)da[2]) | ((unsigned int)f2bf((float)db[2]) << 16);
            pk3[i] = (unsigned int)f2bf((float)da[3]) | ((unsigned int)f2bf((float)db[3]) << 16);
        }
        #pragma unroll
        for (int i = 0; i < 4; ++i) {
            wd0[s*4+i] = pk0[i]; wd1[s*4+i] = pk1[i];
            wd2[s*4+i] = pk2[i]; wd3[s*4+i] = pk3[i];
        }
    }

    // state mapping (tid<256), matching MFMA C layout after the LDS reduce:
    // row b = ((tid>>4)&3)*4 + (tid>>6), col j = tid&15
    const int brow = ((tid >> 4) & 3)*4 + (tid >> 6);
    const int jcol = tid & 15;
    const int bglob = bg*16 + brow;
    const double bj = (double)bias[js*16 + jcol];
    const size_t obase = (size_t)bglob*T*F + js*16 + jcol;
    float* outspk = out;
    float* outmem = out + (size_t)64*T*F;

    double syn = 0.0, mem = 0.0, rst = 0.0;

    __syncthreads();   // W tiles ready (full barrier, once)

    for (int t = 0; t < T; ++t) {
        // x load at top: issued before poll, drains during the spin
        float xv = 0.f;
        if (tid < 256) xv = x[obase + (size_t)t*F];

        double h = 0.0;
        double sbase, mbase;
        if (t > 0) {
            // poll own 128-word slice of previous step's tagged bitmap (relaxed sc1)
            const unsigned int tg = (unsigned int)t;   // tag of step t-1 data
            const unsigned int* slot = gbm + (size_t)(((t-1)&3)*4 + bg)*1024;
            const unsigned int* p0 = slot + wv*128 + lane;
            const unsigned int* p1 = p0 + 64;
            unsigned int v0, v1;
            do {
                v0 = __hip_atomic_load(p0, __ATOMIC_RELAXED, __HIP_MEMORY_SCOPE_AGENT);
                v1 = __hip_atomic_load(p1, __ATOMIC_RELAXED, __HIP_MEMORY_SCOPE_AGENT);
            } while (__any(((v0 >> 16) != tg) | ((v1 >> 16) != tg)));
            // stash data halves in own wave's LDS region (same-wave, no barrier)
            wbm[wv][lane]      = (unsigned short)v0;
            wbm[wv][64 + lane] = (unsigned short)v1;

            // off-chain state precompute (independent of h; xv drained by spin)
            sbase = 0.8*syn + (double)xv + bj;
            mbase = 0.9*mem - rst;

            // MFMA: 4 K-chunks x 4 limbs, exact integer fp32 accumulation
            f32x4 ac0 = {0.f,0.f,0.f,0.f}, ac1 = ac0, ac2 = ac0, ac3 = ac0;
            #pragma unroll
            for (int c4 = 0; c4 < 4; ++c4) {
                const int kc = wv*4 + c4;
                // A-frag: lane supplies A[row=r15][k=q*8+i] -> f = kc*32+q*8+i
                unsigned int us = wbm[wv][(2*c4 + (q >> 1))*16 + r15];
                unsigned int byt = (us >> ((q & 1)*8)) & 0xFFu;
                unsigned int d0 = ((byt&1u)  ?0x3F80u:0u) | ((byt&2u)  ?0x3F800000u:0u);
                unsigned int d1 = ((byt&4u)  ?0x3F80u:0u) | ((byt&8u)  ?0x3F800000u:0u);
                unsigned int d2 = ((byt&16u) ?0x3F80u:0u) | ((byt&32u) ?0x3F800000u:0u);
                unsigned int d3 = ((byt&64u) ?0x3F80u:0u) | ((byt&128u)?0x3F800000u:0u);
                i32x4 ai = {(int)d0, (int)d1, (int)d2, (int)d3};
                bf16x8 a = __builtin_bit_cast(bf16x8, ai);
                size_t fo = (size_t)(kc*64 + lane)*4;
                bf16x8 b0 = *(const bf16x8*)(wd0 + fo);
                bf16x8 b1 = *(const bf16x8*)(wd1 + fo);
                bf16x8 b2 = *(const bf16x8*)(wd2 + fo);
                bf16x8 b3 = *(const bf16x8*)(wd3 + fo);
                ac0 = __builtin_amdgcn_mfma_f32_16x16x32_bf16(a, b0, ac0, 0,0,0);
                ac1 = __builtin_amdgcn_mfma_f32_16x16x32_bf16(a, b1, ac1, 0,0,0);
                ac2 = __builtin_amdgcn_mfma_f32_16x16x32_bf16(a, b2, ac2, 0,0,0);
                ac3 = __builtin_amdgcn_mfma_f32_16x16x32_bf16(a, b3, ac3, 0,0,0);
            }
            // limb recombine in fp64 (exact): weight of limb i = 2^(9i-36)
            const double c0 = 1.0/68719476736.0, c1 = 1.0/134217728.0;
            const double c2 = 1.0/262144.0,      c3 = 1.0/512.0;
            #pragma unroll
            for (int r = 0; r < 4; ++r)
                partD[wv*256 + r*64 + lane] =
                    (double)ac0[r]*c0 + (double)ac1[r]*c1 +
                    (double)ac2[r]*c2 + (double)ac3[r]*c3;

            lds_barrier();   // B1: partD writes(t) before reads(t)

            if (tid < 256) {
                double s0 = partD[0*256 + tid] + partD[1*256 + tid];
                double s1 = partD[2*256 + tid] + partD[3*256 + tid];
                double s2 = partD[4*256 + tid] + partD[5*256 + tid];
                double s3 = partD[6*256 + tid] + partD[7*256 + tid];
                h = (s0 + s1) + (s2 + s3);
            }
        } else {
            sbase = 0.8*syn + (double)xv + bj;
            mbase = 0.9*mem - rst;
        }

        if (tid < 256) {
            syn = sbase + h;
            mem = mbase + syn;
            bool sp = (mem > 1.0);
            unsigned long long m = __ballot(sp);
            // publish FIRST (critical path): wave wv owns rows 4g+wv, g=lane>>4;
            // 16 consecutive words per WG = one 64B line
            if ((lane & 15) == 0) {
                int g = lane >> 4;
                unsigned int word = (unsigned int)((m >> (16*g)) & 0xFFFFull);
                unsigned int val = (((unsigned int)(t + 1)) << 16) | word;
                unsigned int* dst = gbm + (size_t)((t&3)*4 + bg)*1024 + js*16 + (4*g + wv);
                __hip_atomic_store(dst, val, __ATOMIC_RELAXED, __HIP_MEMORY_SCOPE_AGENT);
            }
            rst = sp ? 1.0 : 0.0;
            outspk[obase + (size_t)t*F] = sp ? 1.0f : 0.0f;
            outmem[obase + (size_t)t*F] = (float)mem;
        }

        lds_barrier();   // B2: partD/wbm reads(t) before writes(t+1)
    }
}

extern "C" void kernel_launch(void* const* d_in, const int* in_sizes, int n_in,
                              void* d_out, int out_size, void* d_ws, size_t ws_size,
                              hipStream_t stream) {
    const float* x    = (const float*)d_in[0];
    const float* W    = (const float*)d_in[1];
    const float* bias = (const float*)d_in[2];
    float* out = (float*)d_out;

    // ws: 4-slot ring of tagged bitmaps [slot 0..3][bg 0..3][1024 uints] = 64KB
    unsigned int* gbm = (unsigned int*)d_ws;

    hipMemsetAsync(d_ws, 0, 65536, stream);  // clear tags every launch (replay-safe)
    hipLaunchKernelGGL(snn_persist_kernel, dim3(256), dim3(512), 0, stream,
                       x, W, bias, out, gbm);
}